// Round 4
// baseline (1239.349 us; speedup 1.0000x reference)
//
#include <hip/hip_runtime.h>
#include <math.h>

#define B_ 32
#define L_ 336
#define C_ 321
#define P_ 96
#define E_ 4
#define H_ 2048
#define BC_ (B_*C_)          // 10272
#define KP1 352              // K1 padded to multiple of 32
#define INVc 0.99999500003749969f   // 1/sqrt(1+1e-5)

typedef __attribute__((ext_vector_type(8))) short short8v;
typedef __attribute__((ext_vector_type(4))) float f32x4;

__device__ __forceinline__ float gelu_f(float x) {
    return 0.5f * x * (1.0f + erff(x * 0.70710678118654752440f));
}

__device__ __forceinline__ unsigned rne16(float v) {
    unsigned u = __float_as_uint(v);
    return (u + 0x7fffu + ((u >> 16) & 1u)) >> 16;
}

// ---------------- zero out ----------------
__global__ void k_zero(float* __restrict__ p, int n) {
    int i = blockIdx.x * blockDim.x + threadIdx.x;
    if (i < n) p[i] = 0.f;
}

// ---------------- BN1 + transpose + pyramid pooling (coalesced) ----------------
__global__ __launch_bounds__(256) void k_bnpool(
    const float* __restrict__ x, const float* __restrict__ bw, const float* __restrict__ bb,
    float* __restrict__ h, float* __restrict__ s0, float* __restrict__ s1, float* __restrict__ s2)
{
    __shared__ float t[16][337];
    __shared__ float p2[16][168];
    __shared__ float p1[16][84];
    const int b = blockIdx.y;
    const int c0 = blockIdx.x * 16;
    const int tid = threadIdx.x;
    {
        const int tl = tid >> 4, tc = tid & 15;
        const int c = c0 + tc;
        for (int l0 = 0; l0 < L_; l0 += 16) {
            int l = l0 + tl;
            float v = (c < C_) ? x[((size_t)b * L_ + l) * C_ + c] : 0.f;
            t[tc][l] = v;
        }
    }
    __syncthreads();
    for (int idx = tid; idx < 16 * L_; idx += 256) {
        int tt = idx / L_, l = idx - tt * L_;
        int c = c0 + tt;
        if (c < C_) {
            float v = t[tt][l] * (bw[c * L_ + l] * INVc) + bb[c * L_ + l];
            t[tt][l] = v;
            h[(size_t)(b * C_ + c) * L_ + l] = v;
        }
    }
    __syncthreads();
    for (int idx = tid; idx < 16 * 168; idx += 256) {
        int tt = idx / 168, i = idx - tt * 168;
        int c = c0 + tt;
        float v = 0.5f * (t[tt][2 * i] + t[tt][2 * i + 1]);
        p2[tt][i] = v;
        if (c < C_) s2[(size_t)(b * C_ + c) * 168 + i] = v;
    }
    __syncthreads();
    for (int idx = tid; idx < 16 * 84; idx += 256) {
        int tt = idx / 84, i = idx - tt * 84;
        int c = c0 + tt;
        float v = 0.5f * (p2[tt][2 * i] + p2[tt][2 * i + 1]);
        p1[tt][i] = v;
        if (c < C_) s1[(size_t)(b * C_ + c) * 84 + i] = v;
    }
    __syncthreads();
    for (int idx = tid; idx < 16 * 42; idx += 256) {
        int tt = idx / 42, i = idx - tt * 42;
        int c = c0 + tt;
        float v = 0.5f * (p1[tt][2 * i] + p1[tt][2 * i + 1]);
        if (c < C_) s0[(size_t)(b * C_ + c) * 42 + i] = v;
    }
}

// ---------------- generic guarded GEMM (mixer); optional fused BN2 second output ----
template<int GELU, int ADD, int BN2>
__global__ __launch_bounds__(256) void gemm_kernel(
    const float* __restrict__ A, const float* __restrict__ W,
    const float* __restrict__ bias, const float* __restrict__ S,
    float* __restrict__ D, int M, int N, int K,
    const float* __restrict__ bnw, const float* __restrict__ bnb, float* __restrict__ D2)
{
    __shared__ __align__(16) float As[16][68];
    __shared__ __align__(16) float Ws[16][68];
    int m0 = blockIdx.x * 64, n0 = blockIdx.y * 64;
    int tid = threadIdx.x;
    int tr = tid >> 4, tc = tid & 15;
    float acc[4][4];
    #pragma unroll
    for (int i = 0; i < 4; ++i)
        #pragma unroll
        for (int j = 0; j < 4; ++j) acc[i][j] = 0.f;

    int nk = (K + 15) >> 4;
    for (int kt = 0; kt < nk; ++kt) {
        int k0 = kt * 16;
        #pragma unroll
        for (int it = 0; it < 4; ++it) {
            int elem = tid + it * 256;
            int row = elem >> 4, kk = elem & 15;
            int gm = m0 + row, gk = k0 + kk;
            As[kk][row] = (gm < M && gk < K) ? A[(size_t)gm * K + gk] : 0.f;
            int gn = n0 + row;
            Ws[kk][row] = (gn < N && gk < K) ? W[(size_t)gn * K + gk] : 0.f;
        }
        __syncthreads();
        #pragma unroll
        for (int kk = 0; kk < 16; ++kk) {
            float4 a4 = *reinterpret_cast<const float4*>(&As[kk][tr * 4]);
            float4 w4 = *reinterpret_cast<const float4*>(&Ws[kk][tc * 4]);
            float av[4] = {a4.x, a4.y, a4.z, a4.w};
            float wv[4] = {w4.x, w4.y, w4.z, w4.w};
            #pragma unroll
            for (int i = 0; i < 4; ++i)
                #pragma unroll
                for (int j = 0; j < 4; ++j) acc[i][j] += av[i] * wv[j];
        }
        __syncthreads();
    }
    #pragma unroll
    for (int i = 0; i < 4; ++i) {
        int m = m0 + tr * 4 + i;
        if (m >= M) continue;
        int cch = 0;
        if (BN2) cch = m % C_;
        #pragma unroll
        for (int j = 0; j < 4; ++j) {
            int n = n0 + tc * 4 + j;
            if (n >= N) continue;
            float v = acc[i][j] + bias[n];
            if (GELU) v = gelu_f(v);
            if (ADD) v += S[(size_t)m * N + n];
            D[(size_t)m * N + n] = v;
            if (BN2) {
                D2[(size_t)m * N + n] = v * (bnw[cch * N + n] * INVc) + bnb[cch * N + n];
            }
        }
    }
}

// ---------------- DDI scan -> writes bf16 hi/lo planes (padded to 352) ----------------
__global__ __launch_bounds__(256) void k_ddi(
    const float* __restrict__ d, const float* __restrict__ n1w, const float* __restrict__ n1b,
    const float* __restrict__ aggw, const float* __restrict__ aggb,
    ushort* __restrict__ ahi, ushort* __restrict__ alo)
{
    __shared__ float sAw[144];
    __shared__ float sAb[12];
    int tid = threadIdx.x;
    if (tid < 144) sAw[tid] = aggw[tid];
    if (tid < 12) sAb[tid] = aggb[tid];
    __syncthreads();
    int token = blockIdx.x * blockDim.x + tid;
    if (token >= BC_) return;
    int c = token % C_;
    float w[12], bb[12], prev[12];
    #pragma unroll
    for (int p = 0; p < 12; ++p) { w[p] = n1w[c * 12 + p] * INVc; bb[p] = n1b[c * 12 + p]; }
    const float* drow = d + (size_t)token * L_;
    unsigned* hrow = (unsigned*)(ahi + (size_t)token * KP1);
    unsigned* lrow = (unsigned*)(alo + (size_t)token * KP1);

    auto store12 = [&](int base, const float* v) {
        #pragma unroll
        for (int j = 0; j < 6; ++j) {
            unsigned h0 = rne16(v[2*j]), h1 = rne16(v[2*j+1]);
            float f0 = __uint_as_float(h0 << 16), f1 = __uint_as_float(h1 << 16);
            unsigned l0 = rne16(v[2*j] - f0), l1 = rne16(v[2*j+1] - f1);
            hrow[(base >> 1) + j] = h0 | (h1 << 16);
            lrow[(base >> 1) + j] = l0 | (l1 << 16);
        }
    };

    #pragma unroll
    for (int p = 0; p < 12; ++p) prev[p] = drow[p];
    store12(0, prev);
    for (int t = 0; t < 27; ++t) {
        float inp[12];
        #pragma unroll
        for (int p = 0; p < 12; ++p) inp[p] = prev[p] * w[p] + bb[p];
        float o[12];
        #pragma unroll
        for (int i = 0; i < 12; ++i) {
            float a = sAb[i];
            #pragma unroll
            for (int p = 0; p < 12; ++p) a += inp[p] * sAw[i * 12 + p];
            o[i] = gelu_f(a);
        }
        const float* xp = drow + 12 + t * 12;
        #pragma unroll
        for (int p = 0; p < 12; ++p) prev[p] = o[p] + xp[p];
        store12(12 + t * 12, prev);
    }
    #pragma unroll
    for (int j = 0; j < 8; ++j) { hrow[168 + j] = 0u; lrow[168 + j] = 0u; }
}

// ---------------- gating (wave per token, coalesced) ----------------
__global__ __launch_bounds__(256) void k_gate(
    const float* __restrict__ te, const float* __restrict__ gw,
    const float* __restrict__ gb, float* __restrict__ gates)
{
    __shared__ float gw_s[4][L_];
    int tid = threadIdx.x;
    for (int idx = tid; idx < 4 * L_; idx += 256) gw_s[idx / L_][idx - (idx / L_) * L_] = gw[idx];
    __syncthreads();
    int wv = tid >> 6, lane = tid & 63;
    int token = blockIdx.x * 4 + wv;
    if (token >= BC_) return;
    const float* row = te + (size_t)token * L_;
    float a0 = 0.f, a1 = 0.f, a2 = 0.f, a3 = 0.f;
    for (int l = lane; l < L_; l += 64) {
        float tv = row[l];
        a0 += tv * gw_s[0][l]; a1 += tv * gw_s[1][l];
        a2 += tv * gw_s[2][l]; a3 += tv * gw_s[3][l];
    }
    #pragma unroll
    for (int off = 32; off > 0; off >>= 1) {
        a0 += __shfl_down(a0, off);
        a1 += __shfl_down(a1, off);
        a2 += __shfl_down(a2, off);
        a3 += __shfl_down(a3, off);
    }
    if (lane == 0) {
        float acc[4] = {a0 + gb[0], a1 + gb[1], a2 + gb[2], a3 + gb[3]};
        int im = 0;
        #pragma unroll
        for (int e = 1; e < 4; ++e) if (acc[e] > acc[im]) im = e;
        float second = -1e30f;
        #pragma unroll
        for (int e = 0; e < 4; ++e) if (e != im) second = fmaxf(second, acc[e]);
        float mx = acc[im];
        float s[4]; float ssum = 0.f;
        #pragma unroll
        for (int e = 0; e < 4; ++e) { s[e] = expf(acc[e] - mx); ssum += s[e]; }
        float dec[4]; float dmx = -1e30f;
        #pragma unroll
        for (int e = 0; e < 4; ++e) {
            s[e] /= ssum;
            dec[e] = (acc[e] < second) ? 10.f * logf(s[e] + 1.f) : 10.f * (expf(s[e]) - 1.f);
            dmx = fmaxf(dmx, dec[e]);
        }
        float g[4]; float gsum = 0.f;
        #pragma unroll
        for (int e = 0; e < 4; ++e) { g[e] = expf(dec[e] - dmx); gsum += g[e]; }
        #pragma unroll
        for (int e = 0; e < 4; ++e) gates[token * 4 + e] = g[e] / gsum;
    }
}

// ---------------- split fp32 -> bf16 hi/lo planes (K padded to Kp) ----------------
__global__ void k_split(const float* __restrict__ src, ushort* __restrict__ hi,
                        ushort* __restrict__ lo, int rows, int K, int Kp)
{
    int idx = blockIdx.x * blockDim.x + threadIdx.x;
    if (idx >= rows * Kp) return;
    int r = idx / Kp, k = idx - r * Kp;
    float v = (k < K) ? src[(size_t)r * K + k] : 0.f;
    unsigned h = rne16(v);
    float hf = __uint_as_float(h << 16);
    unsigned l = rne16(v - hf);
    hi[idx] = (ushort)h;
    lo[idx] = (ushort)l;
}

// ---------------- fused expert MLP via bf16x3 MFMA, tile-pinned XCDs ----------------
// Grid 704 (648 active). All 8 (expert x ht-half) blocks of a 128-token tile map to
// bids == tile%8 (mod 8) -> same XCD: the tile's A planes stay L2-resident across the
// 8x re-stream, and out atomics are XCD-local. 512 thr = 8 waves (4 tok-groups x 2 hh).
__global__ __launch_bounds__(512, 4) void k_expert_mfma(
    const ushort* __restrict__ ahi, const ushort* __restrict__ alo,
    const ushort* __restrict__ w1hi, const ushort* __restrict__ w1lo,
    const float* __restrict__ eb1,
    const ushort* __restrict__ w2hi, const ushort* __restrict__ w2lo,
    const float* __restrict__ eb2,
    const float* __restrict__ gates, float* __restrict__ out)
{
    // staging (K-loop phase) and hid buffer (GEMM2 phase) are barrier-separated -> union
    __shared__ __align__(16) union SM {
        struct { ushort Ah[128][32], Al[128][32], Wh[128][32], Wl[128][32]; } st;
        unsigned hid[8][32][36];
    } sm;

    const int bid = blockIdx.x;
    const int t = (bid & 7) + 8 * (bid >> 6);     // token tile 0..87 (>=81 invalid)
    if (t >= 81) return;
    const int s = (bid >> 3) & 7;
    const int e = s >> 1;
    const int hthalf = s & 1;
    const int t0 = t * 128;

    const int tid = threadIdx.x;
    const int lane = tid & 63;
    const int wv = tid >> 6;
    const int g  = wv & 3;          // token group (32 tokens)
    const int hh = wv >> 2;         // h half of the 128-h sweep
    const int l15 = lane & 15;
    const int l4  = lane >> 4;
    const int fgx = (l4 ^ ((l15 >> 1) & 3)) * 8;   // swizzled frag granule (ushort units)

    const int srow = tid >> 2;                      // staging row 0..127
    const int slot = tid & 3;
    const int sws  = (slot ^ ((srow >> 1) & 3)) * 8; // swizzled store offset

    const int tokrow = t0 + srow;
    const bool tok_ok = tokrow < BC_;
    const ushort* Ag_h = ahi + (size_t)tokrow * KP1 + slot * 8;
    const ushort* Ag_l = alo + (size_t)tokrow * KP1 + slot * 8;

    const f32x4 z4 = {0.f, 0.f, 0.f, 0.f};
    f32x4 acc2[2][6];
    #pragma unroll
    for (int m = 0; m < 2; ++m)
        #pragma unroll
        for (int n = 0; n < 6; ++n) acc2[m][n] = z4;

    const uint4 zero4 = make_uint4(0u, 0u, 0u, 0u);
    uint4 pAh, pAl, pWh, pWl;

    // prefetch chunk 0 of sweep 0
    {
        const int hbs = hthalf * 1024;
        const ushort* Wg_h = w1hi + ((size_t)(e * H_ + hbs + srow)) * KP1 + slot * 8;
        const ushort* Wg_l = w1lo + ((size_t)(e * H_ + hbs + srow)) * KP1 + slot * 8;
        pAh = tok_ok ? *(const uint4*)Ag_h : zero4;
        pAl = tok_ok ? *(const uint4*)Ag_l : zero4;
        pWh = *(const uint4*)Wg_h;
        pWl = *(const uint4*)Wg_l;
    }

    for (int s8 = 0; s8 < 8; ++s8) {
        const int hbs = hthalf * 1024 + s8 * 128;
        const ushort* Wg_h = w1hi + ((size_t)(e * H_ + hbs + srow)) * KP1 + slot * 8;
        const ushort* Wg_l = w1lo + ((size_t)(e * H_ + hbs + srow)) * KP1 + slot * 8;

        f32x4 acc1[2][4];
        #pragma unroll
        for (int m = 0; m < 2; ++m)
            #pragma unroll
            for (int n = 0; n < 4; ++n) acc1[m][n] = z4;

        for (int kt = 0; kt < 11; ++kt) {
            __syncthreads();                         // prior phase's LDS reads done
            *(uint4*)&sm.st.Ah[srow][sws] = pAh;
            *(uint4*)&sm.st.Al[srow][sws] = pAl;
            *(uint4*)&sm.st.Wh[srow][sws] = pWh;
            *(uint4*)&sm.st.Wl[srow][sws] = pWl;
            __syncthreads();
            if (kt < 10) {
                const int ko = (kt + 1) * 32;
                pAh = tok_ok ? *(const uint4*)(Ag_h + ko) : zero4;
                pAl = tok_ok ? *(const uint4*)(Ag_l + ko) : zero4;
                pWh = *(const uint4*)(Wg_h + ko);
                pWl = *(const uint4*)(Wg_l + ko);
            }
            short8v aH[2], aL[2];
            #pragma unroll
            for (int m = 0; m < 2; ++m) {
                const int R = g * 32 + m * 16 + l15;
                aH[m] = *(const short8v*)&sm.st.Ah[R][fgx];
                aL[m] = *(const short8v*)&sm.st.Al[R][fgx];
            }
            #pragma unroll
            for (int n = 0; n < 4; ++n) {
                const int R = hh * 64 + n * 16 + l15;
                short8v bH = *(const short8v*)&sm.st.Wh[R][fgx];
                short8v bL = *(const short8v*)&sm.st.Wl[R][fgx];
                #pragma unroll
                for (int m = 0; m < 2; ++m) {
                    acc1[m][n] = __builtin_amdgcn_mfma_f32_16x16x32_bf16(aH[m], bH, acc1[m][n], 0, 0, 0);
                    acc1[m][n] = __builtin_amdgcn_mfma_f32_16x16x32_bf16(aL[m], bH, acc1[m][n], 0, 0, 0);
                    acc1[m][n] = __builtin_amdgcn_mfma_f32_16x16x32_bf16(aH[m], bL, acc1[m][n], 0, 0, 0);
                }
            }
        }
        __syncthreads();    // all staging reads done before hid overwrites the union

        // prefetch chunk 0 of next sweep (hides under GEMM2)
        if (s8 < 7) {
            const int nhbs = hthalf * 1024 + (s8 + 1) * 128;
            const ushort* nWh = w1hi + ((size_t)(e * H_ + nhbs + srow)) * KP1 + slot * 8;
            const ushort* nWl = w1lo + ((size_t)(e * H_ + nhbs + srow)) * KP1 + slot * 8;
            pAh = tok_ok ? *(const uint4*)Ag_h : zero4;
            pAl = tok_ok ? *(const uint4*)Ag_l : zero4;
            pWh = *(const uint4*)nWh;
            pWl = *(const uint4*)nWl;
        }

        // GEMM2: two 32-h passes over this sweep's hid
        #pragma unroll
        for (int p2 = 0; p2 < 2; ++p2) {
            // bias + gelu + split + pack into wave-private hid (granule-rotated)
            #pragma unroll
            for (int np = 0; np < 2; ++np) {
                const int n = p2 * 2 + np;
                const float bv = eb1[e * H_ + hbs + hh * 64 + n * 16 + l15];
                #pragma unroll
                for (int m = 0; m < 2; ++m) {
                    #pragma unroll
                    for (int r = 0; r < 4; ++r) {
                        float v = gelu_f(acc1[m][n][r] + bv);
                        unsigned hbits = rne16(v);
                        unsigned lbits = rne16(v - __uint_as_float(hbits << 16));
                        const int rho = m * 16 + l4 * 4 + r;
                        const int c = np * 16 + l15;
                        const int Gp = ((c >> 2) + 2 * rho) & 7;
                        sm.hid[wv][rho][Gp * 4 + (c & 3)] = hbits | (lbits << 16);
                    }
                }
            }
            // unpack to GEMM2 A-frags (wave-private: HW per-wave lgkmcnt ordering)
            short8v ah2[2], al2[2];
            #pragma unroll
            for (int m = 0; m < 2; ++m) {
                const int rho2 = m * 16 + l15;
                uint4 q0 = *(const uint4*)&sm.hid[wv][rho2][((2 * l4 + 2 * rho2) & 7) * 4];
                uint4 q1 = *(const uint4*)&sm.hid[wv][rho2][((2 * l4 + 1 + 2 * rho2) & 7) * 4];
                unsigned q[8] = {q0.x, q0.y, q0.z, q0.w, q1.x, q1.y, q1.z, q1.w};
                unsigned hi4[4], lo4[4];
                #pragma unroll
                for (int j = 0; j < 4; ++j) {
                    hi4[j] = (q[2*j] & 0xffffu) | (q[2*j+1] << 16);
                    lo4[j] = (q[2*j] >> 16)    | (q[2*j+1] & 0xffff0000u);
                }
                ah2[m] = *(short8v*)hi4;
                al2[m] = *(short8v*)lo4;
            }
            const ushort* w2bh = w2hi + ((size_t)e * P_) * H_ + hbs + hh * 64 + p2 * 32 + l4 * 8;
            const ushort* w2bl = w2lo + ((size_t)e * P_) * H_ + hbs + hh * 64 + p2 * 32 + l4 * 8;
            #pragma unroll
            for (int n2 = 0; n2 < 6; ++n2) {
                short8v b2h = *(const short8v*)(w2bh + (size_t)(n2 * 16 + l15) * H_);
                short8v b2l = *(const short8v*)(w2bl + (size_t)(n2 * 16 + l15) * H_);
                #pragma unroll
                for (int m = 0; m < 2; ++m) {
                    acc2[m][n2] = __builtin_amdgcn_mfma_f32_16x16x32_bf16(ah2[m], b2h, acc2[m][n2], 0, 0, 0);
                    acc2[m][n2] = __builtin_amdgcn_mfma_f32_16x16x32_bf16(al2[m], b2h, acc2[m][n2], 0, 0, 0);
                    acc2[m][n2] = __builtin_amdgcn_mfma_f32_16x16x32_bf16(ah2[m], b2l, acc2[m][n2], 0, 0, 0);
                }
            }
        }
    }

    // epilogue: gate-weighted atomic accumulate (bias added once: hh==0 && hthalf==0)
    #pragma unroll
    for (int m = 0; m < 2; ++m) {
        #pragma unroll
        for (int r = 0; r < 4; ++r) {
            const int tok = t0 + g * 32 + m * 16 + l4 * 4 + r;
            if (tok < BC_) {
                const float gv = gates[tok * 4 + e];
                const int b = tok / C_, c = tok - (tok / C_) * C_;
                float* orow = out + (size_t)b * P_ * C_ + c;
                #pragma unroll
                for (int n = 0; n < 6; ++n) {
                    const int p = n * 16 + l15;
                    float v = acc2[m][n][r];
                    if (hh == 0 && hthalf == 0) v += eb2[e * P_ + p];
                    atomicAdd(orow + (size_t)p * C_, gv * v);
                }
            }
        }
    }
}

// ---------------- launch ----------------
extern "C" void kernel_launch(void* const* d_in, const int* in_sizes, int n_in,
                              void* d_out, int out_size, void* d_ws, size_t ws_size,
                              hipStream_t stream) {
    const float* x       = (const float*)d_in[0];
    const float* mdm_w   = (const float*)d_in[2];
    const float* mdm_b   = (const float*)d_in[3];
    const float* m0w1    = (const float*)d_in[4];
    const float* m0b1    = (const float*)d_in[5];
    const float* m0w2    = (const float*)d_in[6];
    const float* m0b2    = (const float*)d_in[7];
    const float* m1w1    = (const float*)d_in[8];
    const float* m1b1    = (const float*)d_in[9];
    const float* m1w2    = (const float*)d_in[10];
    const float* m1b2    = (const float*)d_in[11];
    const float* m2w1    = (const float*)d_in[12];
    const float* m2b1    = (const float*)d_in[13];
    const float* m2w2    = (const float*)d_in[14];
    const float* m2b2    = (const float*)d_in[15];
    const float* dbn_w   = (const float*)d_in[16];
    const float* dbn_b   = (const float*)d_in[17];
    const float* n1w     = (const float*)d_in[18];
    const float* n1b     = (const float*)d_in[19];
    const float* agg_w   = (const float*)d_in[20];
    const float* agg_b   = (const float*)d_in[21];
    const float* gate_w  = (const float*)d_in[22];
    const float* gate_b  = (const float*)d_in[23];
    const float* ew1     = (const float*)d_in[24];
    const float* eb1     = (const float*)d_in[25];
    const float* ew2     = (const float*)d_in[26];
    const float* eb2     = (const float*)d_in[27];
    float* out = (float*)d_out;

    float* ws   = (float*)d_ws;
    float* h    = ws;                         // BC*336 fp32 (te); later reused for ahi/alo
    float* s0   = h    + (size_t)BC_ * 336;   // BC*42
    float* s1   = s0   + (size_t)BC_ * 42;    // BC*84
    float* s2   = s1   + (size_t)BC_ * 84;    // BC*168
    float* gbuf = s2   + (size_t)BC_ * 168;   // BC*168; later w2 planes
    float* dbuf = gbuf + (size_t)BC_ * 168;   // BC*336; later w1 planes
    float* gates= dbuf + (size_t)BC_ * 336;   // BC*4

    ushort* ahi  = (ushort*)h;                        // BC*352
    ushort* alo  = ahi + (size_t)BC_ * KP1;
    ushort* w2hi = (ushort*)gbuf;                     // 384*2048
    ushort* w2lo = w2hi + (size_t)E_ * P_ * H_;
    ushort* w1hi = (ushort*)dbuf;                     // 8192*352
    ushort* w1lo = w1hi + (size_t)E_ * H_ * KP1;

    const int OUTN = B_ * P_ * C_;
    k_zero<<<(OUTN + 255) / 256, 256, 0, stream>>>(out, OUTN);
    k_bnpool<<<dim3(21, 32), 256, 0, stream>>>(x, mdm_w, mdm_b, h, s0, s1, s2);

    gemm_kernel<1,0,0><<<dim3(161,1), 256, 0, stream>>>(s0,   m0w1, m0b1, nullptr, gbuf, BC_, 42,  42,  nullptr, nullptr, nullptr);
    gemm_kernel<0,1,0><<<dim3(161,2), 256, 0, stream>>>(gbuf, m0w2, m0b2, s1,      s1,   BC_, 84,  42,  nullptr, nullptr, nullptr);
    gemm_kernel<1,0,0><<<dim3(161,2), 256, 0, stream>>>(s1,   m1w1, m1b1, nullptr, gbuf, BC_, 84,  84,  nullptr, nullptr, nullptr);
    gemm_kernel<0,1,0><<<dim3(161,3), 256, 0, stream>>>(gbuf, m1w2, m1b2, s2,      s2,   BC_, 168, 84,  nullptr, nullptr, nullptr);
    gemm_kernel<1,0,0><<<dim3(161,3), 256, 0, stream>>>(s2,   m2w1, m2b1, nullptr, gbuf, BC_, 168, 168, nullptr, nullptr, nullptr);
    // final mixer GEMM with fused BN2 second output (te -> h, d -> dbuf)
    gemm_kernel<0,1,1><<<dim3(161,6), 256, 0, stream>>>(gbuf, m2w2, m2b2, h,       h,    BC_, 336, 168, dbn_w, dbn_b, dbuf);

    k_gate<<<(BC_ + 3) / 4, 256, 0, stream>>>(h, gate_w, gate_b, gates);
    k_ddi<<<(BC_ + 255) / 256, 256, 0, stream>>>(dbuf, n1w, n1b, agg_w, agg_b, ahi, alo);
    {
        int n1 = E_ * H_ * KP1;
        k_split<<<(n1 + 255) / 256, 256, 0, stream>>>(ew1, w1hi, w1lo, E_ * H_, L_, KP1);
        int n2 = E_ * P_ * H_;
        k_split<<<(n2 + 255) / 256, 256, 0, stream>>>(ew2, w2hi, w2lo, E_ * P_, H_, H_);
    }
    k_expert_mfma<<<704, 512, 0, stream>>>(ahi, alo, w1hi, w1lo, eb1,
                                           w2hi, w2lo, eb2, gates, out);
}

// Round 5
// 1159.127 us; speedup vs baseline: 1.0692x; 1.0692x over previous
//
#include <hip/hip_runtime.h>
#include <math.h>

#define B_ 32
#define L_ 336
#define C_ 321
#define P_ 96
#define E_ 4
#define H_ 2048
#define BC_ (B_*C_)          // 10272
#define INVc 0.99999500003749969f   // 1/sqrt(1+1e-5)

typedef __attribute__((ext_vector_type(8))) _Float16 f16x8;
typedef __attribute__((ext_vector_type(16))) float f32x16;
typedef __attribute__((ext_vector_type(2))) int v2i;

__device__ __forceinline__ float gelu_f(float x) {
    return 0.5f * x * (1.0f + erff(x * 0.70710678118654752440f));
}

__device__ __forceinline__ unsigned packh(float a, float b) {
    _Float16 ha = (_Float16)a, hb = (_Float16)b;
    unsigned short ua = __builtin_bit_cast(unsigned short, ha);
    unsigned short ub = __builtin_bit_cast(unsigned short, hb);
    return (unsigned)ua | ((unsigned)ub << 16);
}

// ---------------- zero out ----------------
__global__ void k_zero(float* __restrict__ p, int n) {
    int i = blockIdx.x * blockDim.x + threadIdx.x;
    if (i < n) p[i] = 0.f;
}

// ---------------- BN1 + transpose + pyramid pooling (coalesced) ----------------
__global__ __launch_bounds__(256) void k_bnpool(
    const float* __restrict__ x, const float* __restrict__ bw, const float* __restrict__ bb,
    float* __restrict__ h, float* __restrict__ s0, float* __restrict__ s1, float* __restrict__ s2)
{
    __shared__ float t[16][337];
    __shared__ float p2[16][168];
    __shared__ float p1[16][84];
    const int b = blockIdx.y;
    const int c0 = blockIdx.x * 16;
    const int tid = threadIdx.x;
    {
        const int tl = tid >> 4, tc = tid & 15;
        const int c = c0 + tc;
        for (int l0 = 0; l0 < L_; l0 += 16) {
            int l = l0 + tl;
            float v = (c < C_) ? x[((size_t)b * L_ + l) * C_ + c] : 0.f;
            t[tc][l] = v;
        }
    }
    __syncthreads();
    for (int idx = tid; idx < 16 * L_; idx += 256) {
        int tt = idx / L_, l = idx - tt * L_;
        int c = c0 + tt;
        if (c < C_) {
            float v = t[tt][l] * (bw[c * L_ + l] * INVc) + bb[c * L_ + l];
            t[tt][l] = v;
            h[(size_t)(b * C_ + c) * L_ + l] = v;
        }
    }
    __syncthreads();
    for (int idx = tid; idx < 16 * 168; idx += 256) {
        int tt = idx / 168, i = idx - tt * 168;
        int c = c0 + tt;
        float v = 0.5f * (t[tt][2 * i] + t[tt][2 * i + 1]);
        p2[tt][i] = v;
        if (c < C_) s2[(size_t)(b * C_ + c) * 168 + i] = v;
    }
    __syncthreads();
    for (int idx = tid; idx < 16 * 84; idx += 256) {
        int tt = idx / 84, i = idx - tt * 84;
        int c = c0 + tt;
        float v = 0.5f * (p2[tt][2 * i] + p2[tt][2 * i + 1]);
        p1[tt][i] = v;
        if (c < C_) s1[(size_t)(b * C_ + c) * 84 + i] = v;
    }
    __syncthreads();
    for (int idx = tid; idx < 16 * 42; idx += 256) {
        int tt = idx / 42, i = idx - tt * 42;
        int c = c0 + tt;
        float v = 0.5f * (p1[tt][2 * i] + p1[tt][2 * i + 1]);
        if (c < C_) s0[(size_t)(b * C_ + c) * 42 + i] = v;
    }
}

// ---------------- generic guarded GEMM (mixer, fp32); optional fused BN2 ----------------
template<int GELU, int ADD, int BN2>
__global__ __launch_bounds__(256) void gemm_kernel(
    const float* __restrict__ A, const float* __restrict__ W,
    const float* __restrict__ bias, const float* __restrict__ S,
    float* __restrict__ D, int M, int N, int K,
    const float* __restrict__ bnw, const float* __restrict__ bnb, float* __restrict__ D2)
{
    __shared__ __align__(16) float As[16][68];
    __shared__ __align__(16) float Ws[16][68];
    int m0 = blockIdx.x * 64, n0 = blockIdx.y * 64;
    int tid = threadIdx.x;
    int tr = tid >> 4, tc = tid & 15;
    float acc[4][4];
    #pragma unroll
    for (int i = 0; i < 4; ++i)
        #pragma unroll
        for (int j = 0; j < 4; ++j) acc[i][j] = 0.f;

    int nk = (K + 15) >> 4;
    for (int kt = 0; kt < nk; ++kt) {
        int k0 = kt * 16;
        #pragma unroll
        for (int it = 0; it < 4; ++it) {
            int elem = tid + it * 256;
            int row = elem >> 4, kk = elem & 15;
            int gm = m0 + row, gk = k0 + kk;
            As[kk][row] = (gm < M && gk < K) ? A[(size_t)gm * K + gk] : 0.f;
            int gn = n0 + row;
            Ws[kk][row] = (gn < N && gk < K) ? W[(size_t)gn * K + gk] : 0.f;
        }
        __syncthreads();
        #pragma unroll
        for (int kk = 0; kk < 16; ++kk) {
            float4 a4 = *reinterpret_cast<const float4*>(&As[kk][tr * 4]);
            float4 w4 = *reinterpret_cast<const float4*>(&Ws[kk][tc * 4]);
            float av[4] = {a4.x, a4.y, a4.z, a4.w};
            float wv[4] = {w4.x, w4.y, w4.z, w4.w};
            #pragma unroll
            for (int i = 0; i < 4; ++i)
                #pragma unroll
                for (int j = 0; j < 4; ++j) acc[i][j] += av[i] * wv[j];
        }
        __syncthreads();
    }
    #pragma unroll
    for (int i = 0; i < 4; ++i) {
        int m = m0 + tr * 4 + i;
        if (m >= M) continue;
        int cch = 0;
        if (BN2) cch = m % C_;
        #pragma unroll
        for (int j = 0; j < 4; ++j) {
            int n = n0 + tc * 4 + j;
            if (n >= N) continue;
            float v = acc[i][j] + bias[n];
            if (GELU) v = gelu_f(v);
            if (ADD) v += S[(size_t)m * N + n];
            D[(size_t)m * N + n] = v;
            if (BN2) {
                D2[(size_t)m * N + n] = v * (bnw[cch * N + n] * INVc) + bnb[cch * N + n];
            }
        }
    }
}

// ---------------- DDI scan -> planar fp16 hi/lo planes [tok][336] ----------------
__global__ __launch_bounds__(256) void k_ddi(
    const float* __restrict__ d, const float* __restrict__ n1w, const float* __restrict__ n1b,
    const float* __restrict__ aggw, const float* __restrict__ aggb,
    ushort* __restrict__ ahi, ushort* __restrict__ alo)
{
    __shared__ float sAw[144];
    __shared__ float sAb[12];
    int tid = threadIdx.x;
    if (tid < 144) sAw[tid] = aggw[tid];
    if (tid < 12) sAb[tid] = aggb[tid];
    __syncthreads();
    int token = blockIdx.x * blockDim.x + tid;
    if (token >= BC_) return;
    int c = token % C_;
    float w[12], bb[12], prev[12];
    #pragma unroll
    for (int p = 0; p < 12; ++p) { w[p] = n1w[c * 12 + p] * INVc; bb[p] = n1b[c * 12 + p]; }
    const float* drow = d + (size_t)token * L_;
    unsigned* hrow = (unsigned*)(ahi + (size_t)token * L_);
    unsigned* lrow = (unsigned*)(alo + (size_t)token * L_);

    auto store12 = [&](int base, const float* v) {
        #pragma unroll
        for (int j = 0; j < 6; ++j) {
            float v0 = v[2*j], v1 = v[2*j+1];
            float h0 = (float)(_Float16)v0, h1 = (float)(_Float16)v1;
            hrow[(base >> 1) + j] = packh(v0, v1);
            lrow[(base >> 1) + j] = packh(v0 - h0, v1 - h1);
        }
    };

    #pragma unroll
    for (int p = 0; p < 12; ++p) prev[p] = drow[p];
    store12(0, prev);
    for (int t = 0; t < 27; ++t) {
        float inp[12];
        #pragma unroll
        for (int p = 0; p < 12; ++p) inp[p] = prev[p] * w[p] + bb[p];
        float o[12];
        #pragma unroll
        for (int i = 0; i < 12; ++i) {
            float a = sAb[i];
            #pragma unroll
            for (int p = 0; p < 12; ++p) a += inp[p] * sAw[i * 12 + p];
            o[i] = gelu_f(a);
        }
        const float* xp = drow + 12 + t * 12;
        #pragma unroll
        for (int p = 0; p < 12; ++p) prev[p] = o[p] + xp[p];
        store12(12 + t * 12, prev);
    }
}

// ---------------- gating (wave per token, coalesced; stays fp32) ----------------
__global__ __launch_bounds__(256) void k_gate(
    const float* __restrict__ te, const float* __restrict__ gw,
    const float* __restrict__ gb, float* __restrict__ gates)
{
    __shared__ float gw_s[4][L_];
    int tid = threadIdx.x;
    for (int idx = tid; idx < 4 * L_; idx += 256) gw_s[idx / L_][idx - (idx / L_) * L_] = gw[idx];
    __syncthreads();
    int wv = tid >> 6, lane = tid & 63;
    int token = blockIdx.x * 4 + wv;
    if (token >= BC_) return;
    const float* row = te + (size_t)token * L_;
    float a0 = 0.f, a1 = 0.f, a2 = 0.f, a3 = 0.f;
    for (int l = lane; l < L_; l += 64) {
        float tv = row[l];
        a0 += tv * gw_s[0][l]; a1 += tv * gw_s[1][l];
        a2 += tv * gw_s[2][l]; a3 += tv * gw_s[3][l];
    }
    #pragma unroll
    for (int off = 32; off > 0; off >>= 1) {
        a0 += __shfl_down(a0, off);
        a1 += __shfl_down(a1, off);
        a2 += __shfl_down(a2, off);
        a3 += __shfl_down(a3, off);
    }
    if (lane == 0) {
        float acc[4] = {a0 + gb[0], a1 + gb[1], a2 + gb[2], a3 + gb[3]};
        int im = 0;
        #pragma unroll
        for (int e = 1; e < 4; ++e) if (acc[e] > acc[im]) im = e;
        float second = -1e30f;
        #pragma unroll
        for (int e = 0; e < 4; ++e) if (e != im) second = fmaxf(second, acc[e]);
        float mx = acc[im];
        float s[4]; float ssum = 0.f;
        #pragma unroll
        for (int e = 0; e < 4; ++e) { s[e] = expf(acc[e] - mx); ssum += s[e]; }
        float dec[4]; float dmx = -1e30f;
        #pragma unroll
        for (int e = 0; e < 4; ++e) {
            s[e] /= ssum;
            dec[e] = (acc[e] < second) ? 10.f * logf(s[e] + 1.f) : 10.f * (expf(s[e]) - 1.f);
            dmx = fmaxf(dmx, dec[e]);
        }
        float g[4]; float gsum = 0.f;
        #pragma unroll
        for (int e = 0; e < 4; ++e) { g[e] = expf(dec[e] - dmx); gsum += g[e]; }
        #pragma unroll
        for (int e = 0; e < 4; ++e) gates[token * 4 + e] = g[e] / gsum;
    }
}

// ---------------- pack w1 -> fp16 MFMA-A-operand frags [e][hb64][ks21][lane][8] ----------------
__global__ __launch_bounds__(256) void k_packw1(const float* __restrict__ ew1, uint4* __restrict__ w1f)
{
    int idx = blockIdx.x * 256 + threadIdx.x;   // < 4*64*21*64
    int lane = idx & 63;
    int q = idx >> 6;
    int ks = q % 21;
    int q2 = q / 21;
    int hb = q2 & 63;
    int e = q2 >> 6;
    int row = e * 2048 + hb * 32 + (lane & 31);
    int k = ks * 16 + 8 * (lane >> 5);
    const float* src = ew1 + (size_t)row * L_ + k;
    float4 f0 = *(const float4*)src;
    float4 f1 = *(const float4*)(src + 4);
    uint4 o;
    o.x = packh(f0.x, f0.y); o.y = packh(f0.z, f0.w);
    o.z = packh(f1.x, f1.y); o.w = packh(f1.z, f1.w);
    w1f[idx] = o;
}

// ---------------- pack w2 -> fp16 MFMA-B-operand frags [e][pt3][ks128][lane][8] ----------------
__global__ __launch_bounds__(256) void k_packw2(const float* __restrict__ ew2, uint4* __restrict__ w2f)
{
    int idx = blockIdx.x * 256 + threadIdx.x;   // < 4*3*128*64
    int lane = idx & 63;
    int q = idx >> 6;
    int ks2 = q % 128;
    int q2 = q / 128;
    int pt = q2 % 3;
    int e = q2 / 3;
    int row = e * 96 + pt * 32 + (lane & 31);
    int k = ks2 * 16 + 8 * (lane >> 5);
    const float* src = ew2 + (size_t)row * H_ + k;
    float4 f0 = *(const float4*)src;
    float4 f1 = *(const float4*)(src + 4);
    uint4 o;
    o.x = packh(f0.x, f0.y); o.y = packh(f0.z, f0.w);
    o.z = packh(f1.x, f1.y); o.w = packh(f1.z, f1.w);
    w2f[idx] = o;
}

// ---------------- fused expert MLP: fp16 2-term, swapped GEMM1, permlane GEMM2 ----------------
// grid 648: bid=(g<<3)|(e<<1)|par, tile=2g+par -> expert pinned to XCD pair (w1f L2-resident).
// Block: 512 thr = 8 waves, 64 tokens, full H (4 sweeps x (wave 64h)). No syncthreads in main loop.
__global__ __launch_bounds__(512, 2) void k_expert_mfma(
    const ushort* __restrict__ ahi, const ushort* __restrict__ alo,
    const uint4* __restrict__ w1f, const float* __restrict__ eb1,
    const uint4* __restrict__ w2f, const float* __restrict__ eb2,
    const float* __restrict__ gates, float* __restrict__ out)
{
    __shared__ union {
        uint4 a[2 * 42 * 64];        // [pl][g42][tok64] 16B frags, 86016 B
        float red[64 * 96];          // epilogue reduce
    } sm;

    const int bid = blockIdx.x;
    const int e = (bid & 7) >> 1;
    const int tile = ((bid >> 3) << 1) | (bid & 1);
    if (tile >= 161) return;
    const int t0 = tile * 64;

    const int tid = threadIdx.x;
    const int lane = tid & 63;
    const int wv = tid >> 6;
    const int l31 = lane & 31;
    const int u = lane >> 5;

    // ---- stage token planes into LDS (frag-packed, linear = conflict-free) ----
    #pragma unroll
    for (int it = 0; it < 11; ++it) {
        int gi = it * 8 + wv;
        if (gi < 84) {
            int pl = gi / 42, g = gi % 42, tok = lane;
            uint4 v = make_uint4(0u, 0u, 0u, 0u);
            if (t0 + tok < BC_) {
                const ushort* src = (pl ? alo : ahi) + (size_t)(t0 + tok) * L_ + g * 8;
                v = *(const uint4*)src;
            }
            sm.a[(pl * 42 + g) * 64 + tok] = v;
        }
    }
    __syncthreads();   // the only barrier before the epilogue

    // per-lane LDS byte offsets for B-frags: pl*43008 + ks*2048 + u*1024 + n*512 + l31*16
    const char* lbase = (const char*)sm.a;
    int boff[2][2];
    #pragma unroll
    for (int pl = 0; pl < 2; ++pl)
        #pragma unroll
        for (int n = 0; n < 2; ++n)
            boff[pl][n] = pl * 43008 + u * 1024 + n * 512 + l31 * 16;

    const uint4* w1base = w1f + (size_t)e * 64 * 21 * 64;
    const uint4* w2base = w2f + (size_t)e * 3 * 128 * 64;

    f32x16 acc2[2][3];
    #pragma unroll
    for (int n = 0; n < 2; ++n)
        #pragma unroll
        for (int pt = 0; pt < 3; ++pt)
            #pragma unroll
            for (int r = 0; r < 16; ++r) acc2[n][pt][r] = 0.f;

    for (int s = 0; s < 4; ++s) {
        const int hb0 = s * 16 + wv * 2;

        f32x16 acc1[2][2];
        #pragma unroll
        for (int m = 0; m < 2; ++m)
            #pragma unroll
            for (int n = 0; n < 2; ++n)
                #pragma unroll
                for (int r = 0; r < 16; ++r) acc1[m][n][r] = 0.f;

        // ---- GEMM1: C1^T[h][tok] = W1 . A^T, 2-term on token side ----
        for (int ks = 0; ks < 21; ++ks) {
            f16x8 wf[2];
            #pragma unroll
            for (int m = 0; m < 2; ++m)
                wf[m] = __builtin_bit_cast(f16x8, w1base[((size_t)(hb0 + m) * 21 + ks) * 64 + lane]);
            uint4 bq[2][2];
            #pragma unroll
            for (int pl = 0; pl < 2; ++pl)
                #pragma unroll
                for (int n = 0; n < 2; ++n)
                    bq[pl][n] = *(const uint4*)(lbase + boff[pl][n] + ks * 2048);
            #pragma unroll
            for (int m = 0; m < 2; ++m)
                #pragma unroll
                for (int n = 0; n < 2; ++n) {
                    acc1[m][n] = __builtin_amdgcn_mfma_f32_32x32x16_f16(
                        wf[m], __builtin_bit_cast(f16x8, bq[0][n]), acc1[m][n], 0, 0, 0);
                    acc1[m][n] = __builtin_amdgcn_mfma_f32_32x32x16_f16(
                        wf[m], __builtin_bit_cast(f16x8, bq[1][n]), acc1[m][n], 0, 0, 0);
                }
        }

        // ---- bias + gelu + fp16 split + permlane -> GEMM2 ----
        #pragma unroll
        for (int m = 0; m < 2; ++m) {
            float bia[16];
            #pragma unroll
            for (int r = 0; r < 16; ++r)
                bia[r] = eb1[e * H_ + (hb0 + m) * 32 + (r & 3) + 4 * u + 8 * (r >> 2)];
            float g0[2][16];
            #pragma unroll
            for (int n = 0; n < 2; ++n)
                #pragma unroll
                for (int r = 0; r < 16; ++r)
                    g0[n][r] = gelu_f(acc1[m][n][r] + bia[r]);

            #pragma unroll
            for (int kl = 0; kl < 2; ++kl) {
                const int ks2 = (hb0 + m) * 2 + kl;
                f16x8 w2frag[3];
                #pragma unroll
                for (int pt = 0; pt < 3; ++pt)
                    w2frag[pt] = __builtin_bit_cast(f16x8, w2base[((size_t)pt * 128 + ks2) * 64 + lane]);
                #pragma unroll
                for (int n = 0; n < 2; ++n) {
                    const float* vv = &g0[n][8 * kl];
                    // hi plane
                    unsigned X0 = packh(vv[0], vv[1]), X1 = packh(vv[2], vv[3]);
                    unsigned Y0 = packh(vv[4], vv[5]), Y1 = packh(vv[6], vv[7]);
                    v2i s0v = __builtin_amdgcn_permlane32_swap((int)X0, (int)Y0, false, false);
                    v2i s1v = __builtin_amdgcn_permlane32_swap((int)X1, (int)Y1, false, false);
                    uint4 fh;
                    fh.x = (unsigned)s0v.x; fh.y = (unsigned)s1v.x;
                    fh.z = (unsigned)s0v.y; fh.w = (unsigned)s1v.y;
                    // lo plane (residual)
                    float r0 = vv[0] - (float)(_Float16)vv[0];
                    float r1 = vv[1] - (float)(_Float16)vv[1];
                    float r2 = vv[2] - (float)(_Float16)vv[2];
                    float r3 = vv[3] - (float)(_Float16)vv[3];
                    float r4 = vv[4] - (float)(_Float16)vv[4];
                    float r5 = vv[5] - (float)(_Float16)vv[5];
                    float r6 = vv[6] - (float)(_Float16)vv[6];
                    float r7 = vv[7] - (float)(_Float16)vv[7];
                    unsigned Xl0 = packh(r0, r1), Xl1 = packh(r2, r3);
                    unsigned Yl0 = packh(r4, r5), Yl1 = packh(r6, r7);
                    v2i s2v = __builtin_amdgcn_permlane32_swap((int)Xl0, (int)Yl0, false, false);
                    v2i s3v = __builtin_amdgcn_permlane32_swap((int)Xl1, (int)Yl1, false, false);
                    uint4 fl;
                    fl.x = (unsigned)s2v.x; fl.y = (unsigned)s3v.x;
                    fl.z = (unsigned)s2v.y; fl.w = (unsigned)s3v.y;

                    f16x8 fhv = __builtin_bit_cast(f16x8, fh);
                    f16x8 flv = __builtin_bit_cast(f16x8, fl);
                    #pragma unroll
                    for (int pt = 0; pt < 3; ++pt) {
                        acc2[n][pt] = __builtin_amdgcn_mfma_f32_32x32x16_f16(
                            fhv, w2frag[pt], acc2[n][pt], 0, 0, 0);
                        acc2[n][pt] = __builtin_amdgcn_mfma_f32_32x32x16_f16(
                            flv, w2frag[pt], acc2[n][pt], 0, 0, 0);
                    }
                }
            }
        }
    }

    // ---- epilogue: 8-wave LDS reduce, then gate-weighted global atomics ----
    __syncthreads();
    for (int i = tid; i < 64 * 96; i += 512) sm.red[i] = 0.f;
    __syncthreads();
    #pragma unroll
    for (int n = 0; n < 2; ++n)
        #pragma unroll
        for (int pt = 0; pt < 3; ++pt)
            #pragma unroll
            for (int r = 0; r < 16; ++r) {
                int tl = n * 32 + (r & 3) + 4 * u + 8 * (r >> 2);
                int p = pt * 32 + l31;
                atomicAdd(&sm.red[tl * 96 + p], acc2[n][pt][r]);
            }
    __syncthreads();
    for (int i = tid; i < 64 * 96; i += 512) {
        int tl = i / 96, p = i - tl * 96;
        int tok = t0 + tl;
        if (tok < BC_) {
            float gv = gates[tok * 4 + e];
            int b = tok / C_, c = tok - (tok / C_) * C_;
            atomicAdd(&out[((size_t)b * P_ + p) * C_ + c], gv * (sm.red[i] + eb2[e * P_ + p]));
        }
    }
}

// ---------------- launch ----------------
extern "C" void kernel_launch(void* const* d_in, const int* in_sizes, int n_in,
                              void* d_out, int out_size, void* d_ws, size_t ws_size,
                              hipStream_t stream) {
    const float* x       = (const float*)d_in[0];
    const float* mdm_w   = (const float*)d_in[2];
    const float* mdm_b   = (const float*)d_in[3];
    const float* m0w1    = (const float*)d_in[4];
    const float* m0b1    = (const float*)d_in[5];
    const float* m0w2    = (const float*)d_in[6];
    const float* m0b2    = (const float*)d_in[7];
    const float* m1w1    = (const float*)d_in[8];
    const float* m1b1    = (const float*)d_in[9];
    const float* m1w2    = (const float*)d_in[10];
    const float* m1b2    = (const float*)d_in[11];
    const float* m2w1    = (const float*)d_in[12];
    const float* m2b1    = (const float*)d_in[13];
    const float* m2w2    = (const float*)d_in[14];
    const float* m2b2    = (const float*)d_in[15];
    const float* dbn_w   = (const float*)d_in[16];
    const float* dbn_b   = (const float*)d_in[17];
    const float* n1w     = (const float*)d_in[18];
    const float* n1b     = (const float*)d_in[19];
    const float* agg_w   = (const float*)d_in[20];
    const float* agg_b   = (const float*)d_in[21];
    const float* gate_w  = (const float*)d_in[22];
    const float* gate_b  = (const float*)d_in[23];
    const float* ew1     = (const float*)d_in[24];
    const float* eb1     = (const float*)d_in[25];
    const float* ew2     = (const float*)d_in[26];
    const float* eb2     = (const float*)d_in[27];
    float* out = (float*)d_out;

    float* ws = (float*)d_ws;
    float* h    = ws;                           // 336*BC fp32 (te)
    float* s0   = ws + (size_t)336 * BC_;       // 42*BC
    float* s1   = ws + (size_t)378 * BC_;       // 84*BC
    float* s2   = ws + (size_t)462 * BC_;       // 168*BC  (later: w2f)
    float* gbuf = ws + (size_t)630 * BC_;       // 168*BC  (later: w1f)
    float* dbuf = ws + (size_t)798 * BC_;       // 336*BC
    float* gates= ws + (size_t)1134 * BC_;      // 4*BC

    ushort* ahi = (ushort*)ws;                  // BC*336 fp16 (overlays h, after k_gate)
    ushort* alo = ahi + (size_t)BC_ * L_;       // ends exactly at h-region end
    uint4* w2f = (uint4*)s2;                    // 4*3*128*64 frags = 1.57 MB
    uint4* w1f = (uint4*)gbuf;                  // 4*64*21*64 frags = 5.5 MB

    const int OUTN = B_ * P_ * C_;
    k_zero<<<(OUTN + 255) / 256, 256, 0, stream>>>(out, OUTN);
    k_bnpool<<<dim3(21, 32), 256, 0, stream>>>(x, mdm_w, mdm_b, h, s0, s1, s2);

    gemm_kernel<1,0,0><<<dim3(161,1), 256, 0, stream>>>(s0,   m0w1, m0b1, nullptr, gbuf, BC_, 42,  42,  nullptr, nullptr, nullptr);
    gemm_kernel<0,1,0><<<dim3(161,2), 256, 0, stream>>>(gbuf, m0w2, m0b2, s1,      s1,   BC_, 84,  42,  nullptr, nullptr, nullptr);
    gemm_kernel<1,0,0><<<dim3(161,2), 256, 0, stream>>>(s1,   m1w1, m1b1, nullptr, gbuf, BC_, 84,  84,  nullptr, nullptr, nullptr);
    gemm_kernel<0,1,0><<<dim3(161,3), 256, 0, stream>>>(gbuf, m1w2, m1b2, s2,      s2,   BC_, 168, 84,  nullptr, nullptr, nullptr);
    gemm_kernel<1,0,0><<<dim3(161,3), 256, 0, stream>>>(s2,   m2w1, m2b1, nullptr, gbuf, BC_, 168, 168, nullptr, nullptr, nullptr);
    // s2 free now -> pack w2 into it
    k_packw2<<<(E_*3*128*64) / 256, 256, 0, stream>>>(ew2, w2f);
    // final mixer GEMM with fused BN2 (te -> h, d -> dbuf)
    gemm_kernel<0,1,1><<<dim3(161,6), 256, 0, stream>>>(gbuf, m2w2, m2b2, h,       h,    BC_, 336, 168, dbn_w, dbn_b, dbuf);
    // gbuf free now -> pack w1 into it
    k_packw1<<<(E_*64*21*64) / 256, 256, 0, stream>>>(ew1, w1f);

    k_gate<<<(BC_ + 3) / 4, 256, 0, stream>>>(h, gate_w, gate_b, gates);
    // h free now -> ddi writes fp16 planes over it
    k_ddi<<<(BC_ + 255) / 256, 256, 0, stream>>>(dbuf, n1w, n1b, agg_w, agg_b, ahi, alo);

    k_expert_mfma<<<648, 512, 0, stream>>>(ahi, alo, w1f, eb1, w2f, eb2, gates, out);
}